// Round 14
// baseline (11176.218 us; speedup 1.0000x reference)
//
#include <hip/hip_runtime.h>

// ---- static config (mirrors reference) ----
#define BB   2
#define NN   8192
#define KNN  40
#define SENT 8192
#define G0   17          // ceil coords for dl=0.06, pts in [0,1)
#define G1   9           // for dl=0.12
#define G0_3 (G0*G0*G0)  // 4913
#define G1_3 (G1*G1*G1)  // 729

#define BQT  64          // ball-query block (1 wave)
#define TILE 256         // supports per LDS tile

// d2 exactly as numpy: (dx*dx + dy*dy) + dz*dz, no FMA contraction
__device__ __forceinline__ float sqdist(float qx, float qy, float qz,
                                        float sx, float sy, float sz) {
    float dx = __fsub_rn(qx, sx);
    float dy = __fsub_rn(qy, sy);
    float dz = __fsub_rn(qz, sz);
    return __fadd_rn(__fadd_rn(__fmul_rn(dx, dx), __fmul_rn(dy, dy)),
                     __fmul_rn(dz, dz));
}

// prep: copy pts -> out_points[0], fill layer-2 pool/up with SENTINEL, len[0]
__global__ void prep_kernel(const float* __restrict__ pts, float* __restrict__ dout) {
    const size_t PN = (size_t)BB * NN * 3;
    const size_t IN = (size_t)BB * NN * KNN;
    float* out_points0 = dout;
    float* out_pool2   = dout + 3 * PN + 3 * IN + 2 * IN;
    float* out_up2     = dout + 3 * PN + 6 * IN + 2 * IN;
    float* out_len     = dout + 3 * PN + 9 * IN;
    int i = blockIdx.x * 256 + threadIdx.x;
    if (i < (int)PN) out_points0[i] = pts[i];
    if (i < (int)IN) {
        out_pool2[i] = (float)SENT;
        out_up2[i]   = (float)SENT;
    }
    if (i == 0) { out_len[0] = (float)NN; out_len[1] = (float)NN; }
}

// radius ball query: per-thread top-K insertion sort in LDS (stable, lower-
// index-first on ties; inclusive d2 <= r2)
__global__ __launch_bounds__(BQT) void bq_kernel(
    const float* __restrict__ qpts, const float* __restrict__ spts,
    const int* __restrict__ qlen_ptr, int qlen_const,
    const int* __restrict__ slen_ptr, int slen_const,
    float* __restrict__ out, float r2) {
    __shared__ float stile[TILE * 3];
    __shared__ float d2l[KNN][BQT];
    __shared__ int   idl[KNN][BQT];
    int b = blockIdx.y;
    int t = threadIdx.x;
    int qi = blockIdx.x * BQT + t;
    int qlen = qlen_ptr ? qlen_ptr[b] : qlen_const;
    int slen = slen_ptr ? slen_ptr[b] : slen_const;
    bool qvalid = qi < qlen;
    const float* qp = qpts + ((size_t)b * NN + qi) * 3;
    float qx = qp[0], qy = qp[1], qz = qp[2];
    int cnt = 0;
    float worst = 3.4e38f;
    bool block_active = (blockIdx.x * BQT) < qlen;  // block-uniform
    if (block_active) {
        for (int base = 0; base < slen; base += TILE) {
            int tn = min(TILE, slen - base);
            __syncthreads();
            for (int j = t; j < tn * 3; j += BQT)
                stile[j] = spts[((size_t)b * NN + base) * 3 + j];
            __syncthreads();
            if (qvalid) {
                for (int j = 0; j < tn; ++j) {
                    float d2 = sqdist(qx, qy, qz,
                                      stile[j * 3], stile[j * 3 + 1], stile[j * 3 + 2]);
                    if (d2 > r2) continue;                 // ref keeps d2 <= r^2
                    if (cnt == KNN && d2 >= worst) continue; // tie -> keep lower idx
                    int pos = (cnt < KNN) ? cnt : (KNN - 1);
                    while (pos > 0 && d2l[pos - 1][t] > d2) {
                        d2l[pos][t] = d2l[pos - 1][t];
                        idl[pos][t] = idl[pos - 1][t];
                        --pos;
                    }
                    d2l[pos][t] = d2;
                    idl[pos][t] = base + j;
                    if (cnt < KNN) ++cnt;
                    if (cnt == KNN) worst = d2l[KNN - 1][t];
                }
            }
        }
    }
    float* op = out + ((size_t)b * NN + qi) * KNN;
    for (int k = 0; k < KNN; ++k)
        op[k] = (qvalid && k < cnt) ? (float)idl[k][t] : (float)SENT;
}

// per-point voxel id (f32 division, f32 dl)
__global__ void vid_kernel(const float* __restrict__ pts,
                           const int* __restrict__ len_ptr, int len_const,
                           int* __restrict__ vid, float dlf, int G) {
    int b = blockIdx.y;
    int i = blockIdx.x * 256 + threadIdx.x;
    int len = len_ptr ? len_ptr[b] : len_const;
    if (i >= len) return;
    const float* p = pts + ((size_t)b * NN + i) * 3;
    int cx = (int)floorf(__fdiv_rn(p[0], dlf));
    int cy = (int)floorf(__fdiv_rn(p[1], dlf));
    int cz = (int)floorf(__fdiv_rn(p[2], dlf));
    cx = min(max(cx, 0), G - 1);
    cy = min(max(cy, 0), G - 1);
    cz = min(max(cz, 0), G - 1);
    vid[(size_t)b * NN + i] = (cx * G + cy) * G + cz;  // lexicographic == ref key order
}

// deterministic per-voxel accumulation: ascending index order, f32 adds
__global__ __launch_bounds__(256) void vscan_kernel(
    const float* __restrict__ pts, const int* __restrict__ vid,
    const int* __restrict__ len_ptr, int len_const,
    float* __restrict__ vsum, int* __restrict__ vcnt, int G3) {
    __shared__ int svid[NN];
    int b = blockIdx.y;
    int t = threadIdx.x;
    int len = len_ptr ? len_ptr[b] : len_const;
    const int* vb = vid + (size_t)b * NN;
    for (int i = t; i < len; i += 256) svid[i] = vb[i];
    __syncthreads();
    int v = blockIdx.x * 256 + t;
    if (v >= G3) return;
    float sx = 0.f, sy = 0.f, sz = 0.f;
    int c = 0;
    const float* pb = pts + (size_t)b * NN * 3;
    for (int i = 0; i < len; ++i) {
        if (svid[i] == v) {
            sx = __fadd_rn(sx, pb[i * 3]);
            sy = __fadd_rn(sy, pb[i * 3 + 1]);
            sz = __fadd_rn(sz, pb[i * 3 + 2]);
            ++c;
        }
    }
    size_t o = (size_t)b * G3 + v;
    vsum[o * 3]     = sx;
    vsum[o * 3 + 1] = sy;
    vsum[o * 3 + 2] = sz;
    vcnt[o] = c;
}

// compact occupied voxels in id (== key) order -> padded means + length.
// MEAN = sum * f32(1/cnt)  (reciprocal-multiply — the XLA/fast-math lowering;
// differs from true division by 1 ulp in ~30% of coords for cnt=3,5,6,7,...)
__global__ __launch_bounds__(1024) void compact_kernel(
    const float* __restrict__ vsum, const int* __restrict__ vcnt, int G3,
    float* __restrict__ out_pts, int* __restrict__ len_dev,
    float* __restrict__ len_out_f) {
    __shared__ int wsum[16];
    int b = blockIdx.x;
    int t = threadIdx.x;
    int per = (G3 + 1023) >> 10;
    int start = t * per;
    int end = min(start + per, G3);
    if (start > G3) start = G3;
    int c = 0;
    for (int v = start; v < end; ++v) c += (vcnt[(size_t)b * G3 + v] > 0);
    int lane = t & 63, wid = t >> 6;
    int inc = c;
    for (int d = 1; d < 64; d <<= 1) {
        int u = __shfl_up(inc, d);
        if (lane >= d) inc += u;
    }
    if (lane == 63) wsum[wid] = inc;
    __syncthreads();
    if (t < 16) {
        int wv = wsum[t];
        for (int d = 1; d < 16; d <<= 1) {
            int u = __shfl_up(wv, d);
            if (t >= d) wv += u;
        }
        wsum[t] = wv;
    }
    __syncthreads();
    int excl = inc - c + (wid ? wsum[wid - 1] : 0);
    int total = wsum[15];
    int off = excl;
    for (int v = start; v < end; ++v) {
        int cn = vcnt[(size_t)b * G3 + v];
        if (cn > 0) {
            // correctly-rounded f32 reciprocal of the count, then rn multiply
            float rinv = __frcp_rn((float)cn);
            const float* sp = vsum + ((size_t)b * G3 + v) * 3;
            float* op = out_pts + ((size_t)b * NN + off) * 3;
            op[0] = __fmul_rn(sp[0], rinv);
            op[1] = __fmul_rn(sp[1], rinv);
            op[2] = __fmul_rn(sp[2], rinv);
            ++off;
        }
    }
    for (int r = total + t; r < NN; r += 1024) {
        float* op = out_pts + ((size_t)b * NN + r) * 3;
        op[0] = 0.f; op[1] = 0.f; op[2] = 0.f;
    }
    if (t == 0) {
        len_dev[b] = total;
        len_out_f[b] = (float)total;
    }
}

extern "C" void kernel_launch(void* const* d_in, const int* in_sizes, int n_in,
                              void* d_out, int out_size, void* d_ws, size_t ws_size,
                              hipStream_t stream) {
    const float* pts = (const float*)d_in[0];
    float* dout = (float*)d_out;
    const size_t PN = (size_t)BB * NN * 3;     // 49152
    const size_t IN = (size_t)BB * NN * KNN;   // 655360
    float* out_points = dout;
    float* out_neigh  = dout + 3 * PN;
    float* out_pool   = out_neigh + 3 * IN;
    float* out_up     = out_pool + 3 * IN;
    float* out_len    = out_up + 3 * IN;
    float* pts1 = out_points + PN;       // layer-1 points live directly in d_out
    float* pts2 = out_points + 2 * PN;

    // workspace layout (everything written before read -> no memset needed)
    int*   vid0  = (int*)d_ws;                               // BB*NN
    int*   vid1  = vid0 + (size_t)BB * NN;                   // BB*NN
    float* vsum0 = (float*)(vid1 + (size_t)BB * NN);         // BB*G0_3*3
    int*   vcnt0 = (int*)(vsum0 + (size_t)BB * G0_3 * 3);    // BB*G0_3
    float* vsum1 = (float*)(vcnt0 + (size_t)BB * G0_3);      // BB*G1_3*3
    int*   vcnt1 = (int*)(vsum1 + (size_t)BB * G1_3 * 3);    // BB*G1_3
    int*   len1  = vcnt1 + (size_t)BB * G1_3;
    int*   len2  = len1 + BB;

    // mirror Python double-precision scalar arithmetic, then narrow to f32
    double r_normal = 0.03 * 2.5;                 // 0.075
    double r0 = r_normal;
    double dl0 = 2.0 * r_normal / 2.5;            // 0.06
    float r2_0   = (float)(r0 * r0);
    float r2_up0 = (float)((2.0 * r0) * (2.0 * r0));
    float dlf0   = (float)dl0;
    r_normal *= 2.0;                              // 0.15
    double r1 = r_normal;
    double dl1 = 2.0 * r_normal / 2.5;            // 0.12
    float r2_1   = (float)(r1 * r1);
    float r2_up1 = (float)((2.0 * r1) * (2.0 * r1));
    float dlf1   = (float)dl1;
    r_normal *= 2.0;                              // 0.3
    float r2_2 = (float)(r_normal * r_normal);

    dim3 bqgrid(NN / BQT, BB);
    dim3 vxgrid(NN / 256, BB);
    dim3 vsgrid0((G0_3 + 255) / 256, BB);
    dim3 vsgrid1((G1_3 + 255) / 256, BB);

    prep_kernel<<<(int)((IN + 255) / 256), 256, 0, stream>>>(pts, dout);
    // layer 0
    bq_kernel<<<bqgrid, BQT, 0, stream>>>(pts, pts, nullptr, NN, nullptr, NN,
                                          out_neigh + 0 * IN, r2_0);
    vid_kernel<<<vxgrid, 256, 0, stream>>>(pts, nullptr, NN, vid0, dlf0, G0);
    vscan_kernel<<<vsgrid0, 256, 0, stream>>>(pts, vid0, nullptr, NN, vsum0, vcnt0, G0_3);
    compact_kernel<<<BB, 1024, 0, stream>>>(vsum0, vcnt0, G0_3, pts1, len1, out_len + 2);
    bq_kernel<<<bqgrid, BQT, 0, stream>>>(pts1, pts, len1, 0, nullptr, NN,
                                          out_pool + 0 * IN, r2_0);
    bq_kernel<<<bqgrid, BQT, 0, stream>>>(pts, pts1, nullptr, NN, len1, 0,
                                          out_up + 0 * IN, r2_up0);
    // layer 1
    vid_kernel<<<vxgrid, 256, 0, stream>>>(pts1, len1, 0, vid1, dlf1, G1);
    vscan_kernel<<<vsgrid1, 256, 0, stream>>>(pts1, vid1, len1, 0, vsum1, vcnt1, G1_3);
    compact_kernel<<<BB, 1024, 0, stream>>>(vsum1, vcnt1, G1_3, pts2, len2, out_len + 4);
    bq_kernel<<<bqgrid, BQT, 0, stream>>>(pts1, pts1, len1, 0, len1, 0,
                                          out_neigh + 1 * IN, r2_1);
    bq_kernel<<<bqgrid, BQT, 0, stream>>>(pts2, pts1, len2, 0, len1, 0,
                                          out_pool + 1 * IN, r2_1);
    bq_kernel<<<bqgrid, BQT, 0, stream>>>(pts1, pts2, len1, 0, len2, 0,
                                          out_up + 1 * IN, r2_up1);
    // layer 2
    bq_kernel<<<bqgrid, BQT, 0, stream>>>(pts2, pts2, len2, 0, len2, 0,
                                          out_neigh + 2 * IN, r2_2);
}

// Round 15
// 4002.094 us; speedup vs baseline: 2.7926x; 2.7926x over previous
//
#include <hip/hip_runtime.h>

// ---- static config (mirrors reference) ----
#define BB   2
#define NN   8192
#define KNN  40
#define SENT 8192
#define G0   17          // ceil coords for dl=0.06, pts in [0,1)
#define G1   9           // for dl=0.12
#define G0_3 (G0*G0*G0)  // 4913
#define G1_3 (G1*G1*G1)  // 729

#define BQT  256         // 4 waves per block
#define QB   64          // queries per block (one per lane)
#define NW   4           // waves per block (support-split factor)
#define TILE 256         // supports per staged LDS tile

// d2 exactly as numpy: (dx*dx + dy*dy) + dz*dz, no FMA contraction
__device__ __forceinline__ float sqdist(float qx, float qy, float qz,
                                        float sx, float sy, float sz) {
    float dx = __fsub_rn(qx, sx);
    float dy = __fsub_rn(qy, sy);
    float dz = __fsub_rn(qz, sz);
    return __fadd_rn(__fadd_rn(__fmul_rn(dx, dx), __fmul_rn(dy, dy)),
                     __fmul_rn(dz, dz));
}

// prep: copy pts -> out_points[0], fill layer-2 pool/up with SENTINEL, len[0]
__global__ void prep_kernel(const float* __restrict__ pts, float* __restrict__ dout) {
    const size_t PN = (size_t)BB * NN * 3;
    const size_t IN = (size_t)BB * NN * KNN;
    float* out_points0 = dout;
    float* out_pool2   = dout + 3 * PN + 3 * IN + 2 * IN;
    float* out_up2     = dout + 3 * PN + 6 * IN + 2 * IN;
    float* out_len     = dout + 3 * PN + 9 * IN;
    int i = blockIdx.x * 256 + threadIdx.x;
    if (i < (int)PN) out_points0[i] = pts[i];
    if (i < (int)IN) {
        out_pool2[i] = (float)SENT;
        out_up2[i]   = (float)SENT;
    }
    if (i == 0) { out_len[0] = (float)NN; out_len[1] = (float)NN; }
}

// radius ball query, 4-way support-split:
// - 64 queries per block (lane = query), 4 waves each scan 1/4 of each tile
//   into a private partial top-40 (stable insertion sort, proven semantics)
// - stable 4-way merge by (d2, idx) reproduces the global stable top-40 exactly
__global__ __launch_bounds__(BQT) void bq_kernel(
    const float* __restrict__ qpts, const float* __restrict__ spts,
    const int* __restrict__ qlen_ptr, int qlen_const,
    const int* __restrict__ slen_ptr, int slen_const,
    float* __restrict__ out, float r2) {
    __shared__ float stile[TILE * 3];
    __shared__ float d2l[NW][KNN][QB];
    __shared__ int   idl[NW][KNN][QB];
    __shared__ int   cnts[NW][QB];
    int b = blockIdx.y;
    int t = threadIdx.x;
    int w = t >> 6;          // wave id 0..3
    int lane = t & 63;
    int qbase = blockIdx.x * QB;
    int qi = qbase + lane;
    int qlen = qlen_ptr ? qlen_ptr[b] : qlen_const;
    int slen = slen_ptr ? slen_ptr[b] : slen_const;
    bool qvalid = qi < qlen;
    const float* qp = qpts + ((size_t)b * NN + qi) * 3;
    float qx = qp[0], qy = qp[1], qz = qp[2];
    int cnt = 0;
    float worst = 3.4e38f;
    bool block_active = qbase < qlen;  // block-uniform
    if (block_active) {
        for (int base = 0; base < slen; base += TILE) {
            int tn = min(TILE, slen - base);
            __syncthreads();
            for (int j = t; j < tn * 3; j += BQT)
                stile[j] = spts[((size_t)b * NN + base) * 3 + j];
            __syncthreads();
            if (qvalid) {
                int j0 = w * (TILE / NW);
                int j1 = min(j0 + (TILE / NW), tn);
                for (int j = j0; j < j1; ++j) {
                    float d2 = sqdist(qx, qy, qz,
                                      stile[j * 3], stile[j * 3 + 1], stile[j * 3 + 2]);
                    if (d2 > r2) continue;                 // ref keeps d2 <= r^2
                    if (cnt == KNN && d2 >= worst) continue; // tie -> keep lower idx
                    int pos = (cnt < KNN) ? cnt : (KNN - 1);
                    while (pos > 0 && d2l[w][pos - 1][lane] > d2) {
                        d2l[w][pos][lane] = d2l[w][pos - 1][lane];
                        idl[w][pos][lane] = idl[w][pos - 1][lane];
                        --pos;
                    }
                    d2l[w][pos][lane] = d2;
                    idl[w][pos][lane] = base + j;
                    if (cnt < KNN) ++cnt;
                    if (cnt == KNN) worst = d2l[w][KNN - 1][lane];
                }
            }
        }
    }
    cnts[w][lane] = cnt;
    __syncthreads();
    // stable 4-way merge by (d2, idx): wave 0, lane = query
    if (w == 0) {
        float* op = out + ((size_t)b * NN + qi) * KNN;
        int p0 = 0, p1 = 0, p2 = 0, p3 = 0;
        int c0 = cnts[0][lane], c1 = cnts[1][lane], c2 = cnts[2][lane], c3 = cnts[3][lane];
        for (int k = 0; k < KNN; ++k) {
            float bd = 3.4e38f; int bi = SENT; int bw = -1;
            if (p0 < c0) {
                float d = d2l[0][p0][lane]; int id = idl[0][p0][lane];
                if (d < bd || (d == bd && id < bi)) { bd = d; bi = id; bw = 0; }
            }
            if (p1 < c1) {
                float d = d2l[1][p1][lane]; int id = idl[1][p1][lane];
                if (d < bd || (d == bd && id < bi)) { bd = d; bi = id; bw = 1; }
            }
            if (p2 < c2) {
                float d = d2l[2][p2][lane]; int id = idl[2][p2][lane];
                if (d < bd || (d == bd && id < bi)) { bd = d; bi = id; bw = 2; }
            }
            if (p3 < c3) {
                float d = d2l[3][p3][lane]; int id = idl[3][p3][lane];
                if (d < bd || (d == bd && id < bi)) { bd = d; bi = id; bw = 3; }
            }
            float v;
            if (bw >= 0) {
                v = (float)bi;
                if (bw == 0) ++p0; else if (bw == 1) ++p1; else if (bw == 2) ++p2; else ++p3;
            } else {
                v = (float)SENT;
            }
            op[k] = v;
        }
    }
}

// per-point voxel id (f32 division, f32 dl)
__global__ void vid_kernel(const float* __restrict__ pts,
                           const int* __restrict__ len_ptr, int len_const,
                           int* __restrict__ vid, float dlf, int G) {
    int b = blockIdx.y;
    int i = blockIdx.x * 256 + threadIdx.x;
    int len = len_ptr ? len_ptr[b] : len_const;
    if (i >= len) return;
    const float* p = pts + ((size_t)b * NN + i) * 3;
    int cx = (int)floorf(__fdiv_rn(p[0], dlf));
    int cy = (int)floorf(__fdiv_rn(p[1], dlf));
    int cz = (int)floorf(__fdiv_rn(p[2], dlf));
    cx = min(max(cx, 0), G - 1);
    cy = min(max(cy, 0), G - 1);
    cz = min(max(cz, 0), G - 1);
    vid[(size_t)b * NN + i] = (cx * G + cy) * G + cz;  // lexicographic == ref key order
}

// deterministic per-voxel accumulation: ascending index order, f32 adds
__global__ __launch_bounds__(256) void vscan_kernel(
    const float* __restrict__ pts, const int* __restrict__ vid,
    const int* __restrict__ len_ptr, int len_const,
    float* __restrict__ vsum, int* __restrict__ vcnt, int G3) {
    __shared__ int svid[NN];
    int b = blockIdx.y;
    int t = threadIdx.x;
    int len = len_ptr ? len_ptr[b] : len_const;
    const int* vb = vid + (size_t)b * NN;
    for (int i = t; i < len; i += 256) svid[i] = vb[i];
    __syncthreads();
    int v = blockIdx.x * 256 + t;
    if (v >= G3) return;
    float sx = 0.f, sy = 0.f, sz = 0.f;
    int c = 0;
    const float* pb = pts + (size_t)b * NN * 3;
    for (int i = 0; i < len; ++i) {
        if (svid[i] == v) {
            sx = __fadd_rn(sx, pb[i * 3]);
            sy = __fadd_rn(sy, pb[i * 3 + 1]);
            sz = __fadd_rn(sz, pb[i * 3 + 2]);
            ++c;
        }
    }
    size_t o = (size_t)b * G3 + v;
    vsum[o * 3]     = sx;
    vsum[o * 3 + 1] = sy;
    vsum[o * 3 + 2] = sz;
    vcnt[o] = c;
}

// compact occupied voxels in id (== key) order -> padded means + length.
// MEAN = sum * f32(1/cnt) (reciprocal-multiply — matches the np reference
// EXACTLY; verified bit-exact in R14. DO NOT change to true division.)
__global__ __launch_bounds__(1024) void compact_kernel(
    const float* __restrict__ vsum, const int* __restrict__ vcnt, int G3,
    float* __restrict__ out_pts, int* __restrict__ len_dev,
    float* __restrict__ len_out_f) {
    __shared__ int wsum[16];
    int b = blockIdx.x;
    int t = threadIdx.x;
    int per = (G3 + 1023) >> 10;
    int start = t * per;
    int end = min(start + per, G3);
    if (start > G3) start = G3;
    int c = 0;
    for (int v = start; v < end; ++v) c += (vcnt[(size_t)b * G3 + v] > 0);
    int lane = t & 63, wid = t >> 6;
    int inc = c;
    for (int d = 1; d < 64; d <<= 1) {
        int u = __shfl_up(inc, d);
        if (lane >= d) inc += u;
    }
    if (lane == 63) wsum[wid] = inc;
    __syncthreads();
    if (t < 16) {
        int wv = wsum[t];
        for (int d = 1; d < 16; d <<= 1) {
            int u = __shfl_up(wv, d);
            if (t >= d) wv += u;
        }
        wsum[t] = wv;
    }
    __syncthreads();
    int excl = inc - c + (wid ? wsum[wid - 1] : 0);
    int total = wsum[15];
    int off = excl;
    for (int v = start; v < end; ++v) {
        int cn = vcnt[(size_t)b * G3 + v];
        if (cn > 0) {
            float rinv = __frcp_rn((float)cn);
            const float* sp = vsum + ((size_t)b * G3 + v) * 3;
            float* op = out_pts + ((size_t)b * NN + off) * 3;
            op[0] = __fmul_rn(sp[0], rinv);
            op[1] = __fmul_rn(sp[1], rinv);
            op[2] = __fmul_rn(sp[2], rinv);
            ++off;
        }
    }
    for (int r = total + t; r < NN; r += 1024) {
        float* op = out_pts + ((size_t)b * NN + r) * 3;
        op[0] = 0.f; op[1] = 0.f; op[2] = 0.f;
    }
    if (t == 0) {
        len_dev[b] = total;
        len_out_f[b] = (float)total;
    }
}

extern "C" void kernel_launch(void* const* d_in, const int* in_sizes, int n_in,
                              void* d_out, int out_size, void* d_ws, size_t ws_size,
                              hipStream_t stream) {
    const float* pts = (const float*)d_in[0];
    float* dout = (float*)d_out;
    const size_t PN = (size_t)BB * NN * 3;     // 49152
    const size_t IN = (size_t)BB * NN * KNN;   // 655360
    float* out_points = dout;
    float* out_neigh  = dout + 3 * PN;
    float* out_pool   = out_neigh + 3 * IN;
    float* out_up     = out_pool + 3 * IN;
    float* out_len    = out_up + 3 * IN;
    float* pts1 = out_points + PN;       // layer-1 points live directly in d_out
    float* pts2 = out_points + 2 * PN;

    // workspace layout (everything written before read -> no memset needed)
    int*   vid0  = (int*)d_ws;                               // BB*NN
    int*   vid1  = vid0 + (size_t)BB * NN;                   // BB*NN
    float* vsum0 = (float*)(vid1 + (size_t)BB * NN);         // BB*G0_3*3
    int*   vcnt0 = (int*)(vsum0 + (size_t)BB * G0_3 * 3);    // BB*G0_3
    float* vsum1 = (float*)(vcnt0 + (size_t)BB * G0_3);      // BB*G1_3*3
    int*   vcnt1 = (int*)(vsum1 + (size_t)BB * G1_3 * 3);    // BB*G1_3
    int*   len1  = vcnt1 + (size_t)BB * G1_3;
    int*   len2  = len1 + BB;

    // mirror Python double-precision scalar arithmetic, then narrow to f32
    double r_normal = 0.03 * 2.5;                 // 0.075
    double r0 = r_normal;
    double dl0 = 2.0 * r_normal / 2.5;            // 0.06
    float r2_0   = (float)(r0 * r0);
    float r2_up0 = (float)((2.0 * r0) * (2.0 * r0));
    float dlf0   = (float)dl0;
    r_normal *= 2.0;                              // 0.15
    double r1 = r_normal;
    double dl1 = 2.0 * r_normal / 2.5;            // 0.12
    float r2_1   = (float)(r1 * r1);
    float r2_up1 = (float)((2.0 * r1) * (2.0 * r1));
    float dlf1   = (float)dl1;
    r_normal *= 2.0;                              // 0.3
    float r2_2 = (float)(r_normal * r_normal);

    dim3 bqgrid(NN / QB, BB);
    dim3 vxgrid(NN / 256, BB);
    dim3 vsgrid0((G0_3 + 255) / 256, BB);
    dim3 vsgrid1((G1_3 + 255) / 256, BB);

    prep_kernel<<<(int)((IN + 255) / 256), 256, 0, stream>>>(pts, dout);
    // layer 0
    bq_kernel<<<bqgrid, BQT, 0, stream>>>(pts, pts, nullptr, NN, nullptr, NN,
                                          out_neigh + 0 * IN, r2_0);
    vid_kernel<<<vxgrid, 256, 0, stream>>>(pts, nullptr, NN, vid0, dlf0, G0);
    vscan_kernel<<<vsgrid0, 256, 0, stream>>>(pts, vid0, nullptr, NN, vsum0, vcnt0, G0_3);
    compact_kernel<<<BB, 1024, 0, stream>>>(vsum0, vcnt0, G0_3, pts1, len1, out_len + 2);
    bq_kernel<<<bqgrid, BQT, 0, stream>>>(pts1, pts, len1, 0, nullptr, NN,
                                          out_pool + 0 * IN, r2_0);
    bq_kernel<<<bqgrid, BQT, 0, stream>>>(pts, pts1, nullptr, NN, len1, 0,
                                          out_up + 0 * IN, r2_up0);
    // layer 1
    vid_kernel<<<vxgrid, 256, 0, stream>>>(pts1, len1, 0, vid1, dlf1, G1);
    vscan_kernel<<<vsgrid1, 256, 0, stream>>>(pts1, vid1, len1, 0, vsum1, vcnt1, G1_3);
    compact_kernel<<<BB, 1024, 0, stream>>>(vsum1, vcnt1, G1_3, pts2, len2, out_len + 4);
    bq_kernel<<<bqgrid, BQT, 0, stream>>>(pts1, pts1, len1, 0, len1, 0,
                                          out_neigh + 1 * IN, r2_1);
    bq_kernel<<<bqgrid, BQT, 0, stream>>>(pts2, pts1, len2, 0, len1, 0,
                                          out_pool + 1 * IN, r2_1);
    bq_kernel<<<bqgrid, BQT, 0, stream>>>(pts1, pts2, len1, 0, len2, 0,
                                          out_up + 1 * IN, r2_up1);
    // layer 2
    bq_kernel<<<bqgrid, BQT, 0, stream>>>(pts2, pts2, len2, 0, len2, 0,
                                          out_neigh + 2 * IN, r2_2);
}